// Round 1
// baseline (166.981 us; speedup 1.0000x reference)
//
#include <hip/hip_runtime.h>

// NeighbourCovariance: V=200000, C=3, F=16, K=32
// out[v] = [cov_flat (F*6=96), mean_flat (F*3=48)] -> 144 f32 per vertex.

#define EPS 1e-6f

constexpr int C_DIM = 3;
constexpr int F_DIM = 16;
constexpr int K_N = 32;
constexpr int V_PER_BLOCK = 64;   // 256 threads, 4 threads/vertex
constexpr int THREADS = 256;

__global__ __launch_bounds__(THREADS) void neigh_cov_kernel(
    const float* __restrict__ coords,   // [V,3]
    const float* __restrict__ feats,    // [V,16]
    const int*   __restrict__ nidx,     // [V,32]
    float*       __restrict__ out,      // [V,144]
    int V)
{
  // Stage this block's neighbor indices in LDS.
  // Pad stride to 33 so the 16 distinct addresses a wave reads at fixed k
  // hit 16 distinct banks (stride 32 would put them all on one bank).
  __shared__ int sidx[V_PER_BLOCK][K_N + 1];

  const int tid = threadIdx.x;
  const int block_v0 = blockIdx.x * V_PER_BLOCK;

  {
    const long long base = (long long)block_v0 * K_N;
    const long long avail = (long long)V * K_N - base;   // elements left
    #pragma unroll
    for (int i = tid; i < V_PER_BLOCK * K_N; i += THREADS) {
      int val = (i < avail) ? nidx[base + i] : 0;
      sidx[i / K_N][i % K_N] = val;
    }
  }
  __syncthreads();

  const int vloc = tid >> 2;   // 0..63 vertex within block
  const int t    = tid & 3;    // feature quad: features 4t..4t+3
  const int v    = block_v0 + vloc;
  if (v >= V) return;

  float s[4]   = {0.f, 0.f, 0.f, 0.f};
  float wx0[4] = {0.f, 0.f, 0.f, 0.f};
  float wx1[4] = {0.f, 0.f, 0.f, 0.f};
  float wx2[4] = {0.f, 0.f, 0.f, 0.f};
  float e00[4] = {0.f, 0.f, 0.f, 0.f};
  float e10[4] = {0.f, 0.f, 0.f, 0.f};
  float e11[4] = {0.f, 0.f, 0.f, 0.f};
  float e20[4] = {0.f, 0.f, 0.f, 0.f};
  float e21[4] = {0.f, 0.f, 0.f, 0.f};
  float e22[4] = {0.f, 0.f, 0.f, 0.f};

  #pragma unroll 4
  for (int k = 0; k < K_N; ++k) {
    const int idx = sidx[vloc][k];
    // Feature quad: 16B coalesced per lane (64B per vertex group).
    const float4 w4 = *reinterpret_cast<const float4*>(
        feats + (size_t)idx * F_DIM + t * 4);
    // Coordinates: broadcast across the 4 lanes of this vertex.
    const float x0 = coords[(size_t)idx * C_DIM + 0];
    const float x1 = coords[(size_t)idx * C_DIM + 1];
    const float x2 = coords[(size_t)idx * C_DIM + 2];

    const float xx00 = x0 * x0;
    const float xx10 = x1 * x0;
    const float xx11 = x1 * x1;
    const float xx20 = x2 * x0;
    const float xx21 = x2 * x1;
    const float xx22 = x2 * x2;

    const float wv[4] = {w4.x, w4.y, w4.z, w4.w};
    #pragma unroll
    for (int j = 0; j < 4; ++j) {
      const float w = wv[j];
      s[j]   += w;
      wx0[j] = fmaf(w, x0, wx0[j]);
      wx1[j] = fmaf(w, x1, wx1[j]);
      wx2[j] = fmaf(w, x2, wx2[j]);
      e00[j] = fmaf(w, xx00, e00[j]);
      e10[j] = fmaf(w, xx10, e10[j]);
      e11[j] = fmaf(w, xx11, e11[j]);
      e20[j] = fmaf(w, xx20, e20[j]);
      e21[j] = fmaf(w, xx21, e21[j]);
      e22[j] = fmaf(w, xx22, e22[j]);
    }
  }

  // Epilogue: cov (lower-tri order (0,0),(1,0),(1,1),(2,0),(2,1),(2,2)) + mean.
  float cov[24];
  float mn[12];
  #pragma unroll
  for (int j = 0; j < 4; ++j) {
    const float iw = 1.0f / (s[j] + EPS);
    const float m0 = wx0[j] * iw;
    const float m1 = wx1[j] * iw;
    const float m2 = wx2[j] * iw;
    cov[j * 6 + 0] = fmaf(-m0, m0, e00[j] * iw);
    cov[j * 6 + 1] = fmaf(-m1, m0, e10[j] * iw);
    cov[j * 6 + 2] = fmaf(-m1, m1, e11[j] * iw);
    cov[j * 6 + 3] = fmaf(-m2, m0, e20[j] * iw);
    cov[j * 6 + 4] = fmaf(-m2, m1, e21[j] * iw);
    cov[j * 6 + 5] = fmaf(-m2, m2, e22[j] * iw);
    mn[j * 3 + 0] = m0;
    mn[j * 3 + 1] = m1;
    mn[j * 3 + 2] = m2;
  }

  // Vectorized stores: all offsets 16B-aligned.
  float* outv = out + (size_t)v * 144;
  float4* cdst = reinterpret_cast<float4*>(outv + t * 24);       // 24 floats
  const float4* csrc = reinterpret_cast<const float4*>(cov);
  #pragma unroll
  for (int q = 0; q < 6; ++q) cdst[q] = csrc[q];
  float4* mdst = reinterpret_cast<float4*>(outv + 96 + t * 12);  // 12 floats
  const float4* msrc = reinterpret_cast<const float4*>(mn);
  #pragma unroll
  for (int q = 0; q < 3; ++q) mdst[q] = msrc[q];
}

extern "C" void kernel_launch(void* const* d_in, const int* in_sizes, int n_in,
                              void* d_out, int out_size, void* d_ws, size_t ws_size,
                              hipStream_t stream) {
  const float* coords = (const float*)d_in[0];
  const float* feats  = (const float*)d_in[1];
  const int*   nidx   = (const int*)d_in[2];
  float* out = (float*)d_out;

  const int V = in_sizes[0] / C_DIM;   // 200000
  const int blocks = (V + V_PER_BLOCK - 1) / V_PER_BLOCK;

  neigh_cov_kernel<<<blocks, THREADS, 0, stream>>>(coords, feats, nidx, out, V);
}